// Round 1
// baseline (2391.476 us; speedup 1.0000x reference)
//
#include <hip/hip_runtime.h>
#include <math.h>

#define N_NODES  50000
#define N_EDGES  400000
#define N_GRAPHS 500

// ---------- helpers ----------
__device__ __forceinline__ float elu_f(float v) { return v > 0.f ? v : expm1f(v); }

// order-preserving float -> uint32 (for atomic max on floats incl. negatives/-inf)
__device__ __forceinline__ unsigned enc_f(float f) {
    unsigned u = __float_as_uint(f);
    return (u & 0x80000000u) ? ~u : (u | 0x80000000u);
}
__device__ __forceinline__ float dec_f(unsigned u) {
    return __uint_as_float((u & 0x80000000u) ? (u & 0x7FFFFFFFu) : ~u);
}

// ---------- 1) scatter-add message passing (full + occupied masks) ----------
// one wave = one edge; lane j handles feature j -> coalesced 256B atomic RMW
__global__ void k_scatter(const float* __restrict__ x, const int* __restrict__ src,
                          const int* __restrict__ dst, const unsigned char* __restrict__ state,
                          float* __restrict__ aggf, float* __restrict__ aggo)
{
    unsigned idx = blockIdx.x * 256u + threadIdx.x;
    int e = idx >> 6;
    int j = idx & 63;
    if (e >= N_EDGES) return;
    int s = src[e], d = dst[e];
    float v = x[s * 64 + j];
    atomicAdd(&aggf[d * 64 + j], v);
    if (state[e]) atomicAdd(&aggo[d * 64 + j], v);
}

// ---------- 2) node reps: elu((x+aggf)@Wg+bg) - elu((x+aggo)@Wg+bg) ----------
// 8 nodes per block; thread (n, o): o in [0,32)
__global__ void k_nodereps(const float* __restrict__ x, const float* __restrict__ aggf,
                           const float* __restrict__ aggo, const float* __restrict__ Wg,
                           const float* __restrict__ bg, float* __restrict__ reps)
{
    int t = threadIdx.x;
    int n = blockIdx.x * 8 + (t >> 5);
    int o = t & 31;
    if (n >= N_NODES) return;
    const float* xr = x    + n * 64;
    const float* af = aggf + n * 64;
    const float* ao = aggo + n * 64;
    float accf = 0.f, acco = 0.f;
    #pragma unroll 8
    for (int i = 0; i < 64; ++i) {
        float w = Wg[i * 32 + o];
        accf += (xr[i] + af[i]) * w;
        acco += (xr[i] + ao[i]) * w;
    }
    float b = bg[o];
    reps[n * 32 + o] = elu_f(accf + b) - elu_f(acco + b);
}

// ---------- 3) fused per-edge MLP ----------
// block = 256 threads, tile = 32 edges. Activations ping-pong in LDS.
// Each thread computes NO outputs x NE edges; weights from global (L1/L2-hot).
template<int IN, int OUT, int NO, int NE, bool ACT>
__device__ __forceinline__ void mlp_layer(const float* __restrict__ W, const float* __restrict__ B,
                                          const float* sIn, float* sOut, int t)
{
    constexpr int OG = OUT / NO;       // threads along outputs
    constexpr int EG = 256 / OG;       // edge groups
    static_assert(EG * NE == 32, "tile mismatch");
    const int o0 = t % OG;
    const int e0 = (t / OG) * NE;

    float acc[NO][NE];
    #pragma unroll
    for (int a = 0; a < NO; ++a)
        #pragma unroll
        for (int e = 0; e < NE; ++e) acc[a][e] = 0.f;

    for (int i = 0; i < IN; i += 4) {
        float w[NO][4];
        #pragma unroll
        for (int a = 0; a < NO; ++a)
            #pragma unroll
            for (int k = 0; k < 4; ++k)
                w[a][k] = W[(i + k) * OUT + o0 + a * OG];
        #pragma unroll
        for (int e = 0; e < NE; ++e) {
            float4 v = *reinterpret_cast<const float4*>(sIn + (e0 + e) * IN + i);
            #pragma unroll
            for (int a = 0; a < NO; ++a)
                acc[a][e] += v.x * w[a][0] + v.y * w[a][1] + v.z * w[a][2] + v.w * w[a][3];
        }
    }
    __syncthreads();   // everyone done reading sIn before sOut (2-buffer ping-pong) is overwritten
    #pragma unroll
    for (int a = 0; a < NO; ++a) {
        int o = o0 + a * OG;
        float bb = B[o];
        #pragma unroll
        for (int e = 0; e < NE; ++e) {
            float v = acc[a][e] + bb;
            if (ACT) v = elu_f(v);
            sOut[(e0 + e) * OUT + o] = v;
        }
    }
    __syncthreads();
}

__global__ __launch_bounds__(256) void k_mlp(
    const float* __restrict__ reps, const int* __restrict__ src, const int* __restrict__ dst,
    const unsigned char* __restrict__ state, const int* __restrict__ batch, const int* __restrict__ y,
    const float* __restrict__ W1, const float* __restrict__ b1,
    const float* __restrict__ W2, const float* __restrict__ b2,
    const float* __restrict__ W3, const float* __restrict__ b3,
    const float* __restrict__ P1, const float* __restrict__ pb1,
    const float* __restrict__ P2, const float* __restrict__ pb2,
    float* __restrict__ lg_out, unsigned* __restrict__ m_u)
{
    __shared__ float sA[32 * 128];   // widths 64 (in), 128 (L2 out), 64 (L4 out)
    __shared__ float sB[32 * 256];   // widths 256 (L1 out), 64 (L3 out)
    __shared__ int   sSrc[32], sDst[32], sG[32], sCol[32];
    __shared__ unsigned char sAvail[32];

    const int t = threadIdx.x;
    const int ebase = blockIdx.x * 32;

    if (t < 32) {
        int e = ebase + t;
        int s = src[e];
        sSrc[t] = s;
        sDst[t] = dst[e];
        int g = batch[s];
        sG[t] = g;
        sCol[t] = y[g];
        sAvail[t] = state[e] ? 0 : 1;
    }
    __syncthreads();

    // stage concat(reps[src], reps[dst]) -> sA[e][0:64]
    #pragma unroll
    for (int k = 0; k < 8; ++k) {
        int li = k * 256 + t;
        int e = li >> 6, j = li & 63;
        float v = (j < 32) ? reps[sSrc[e] * 32 + j] : reps[sDst[e] * 32 + (j - 32)];
        sA[e * 64 + j] = v;
    }
    __syncthreads();

    mlp_layer< 64, 256, 2, 16, true >(W1, b1, sA, sB, t);  // L1 + ELU
    mlp_layer<256, 128, 2,  8, true >(W2, b2, sB, sA, t);  // L2 + ELU
    mlp_layer<128,  64, 2,  4, false>(W3, b3, sA, sB, t);  // L3 (no act)
    mlp_layer< 64,  64, 2,  4, true >(P1, pb1, sB, sA, t); // P1 + ELU

    // final: lg = t_act . P2[:, y[g]] + pb2[y[g]]
    if (t < 32) {
        int e = t;
        int col = sCol[e];
        float acc = pb2[col];
        #pragma unroll 8
        for (int j = 0; j < 64; ++j)
            acc += sA[e * 64 + j] * P2[j * 10 + col];
        lg_out[ebase + e] = acc;
        float lgm = sAvail[e] ? acc : -INFINITY;
        atomicMax(&m_u[sG[e]], enc_f(lgm));
    }
}

// ---------- 4) softmax pieces ----------
__global__ void k_ex(const float* __restrict__ lg, const int* __restrict__ src,
                     const unsigned char* __restrict__ state, const int* __restrict__ batch,
                     const unsigned* __restrict__ m_u, float* __restrict__ ex,
                     float* __restrict__ denom)
{
    int e = blockIdx.x * 256 + threadIdx.x;
    if (e >= N_EDGES) return;
    int g = batch[src[e]];
    float v = 0.f;
    if (!state[e]) v = expf(lg[e] - dec_f(m_u[g]));
    ex[e] = v;
    atomicAdd(&denom[g], v);
}

__global__ void k_probs(const float* __restrict__ ex, const int* __restrict__ src,
                        const unsigned char* __restrict__ state, const int* __restrict__ batch,
                        const float* __restrict__ denom, float* __restrict__ out,
                        unsigned* __restrict__ maxp_u)
{
    int e = blockIdx.x * 256 + threadIdx.x;
    if (e >= N_EDGES) return;
    int g = batch[src[e]];
    float p = ex[e] / denom[g];
    out[e] = p;
    float mp = state[e] ? -INFINITY : p;
    atomicMax(&maxp_u[g], enc_f(mp));
}

__global__ void k_argmax(const float* __restrict__ out, const int* __restrict__ src,
                         const unsigned char* __restrict__ state, const int* __restrict__ batch,
                         const unsigned* __restrict__ maxp_u, unsigned* __restrict__ act_u)
{
    int e = blockIdx.x * 256 + threadIdx.x;
    if (e >= N_EDGES) return;
    int g = batch[src[e]];
    float mp = state[e] ? -INFINITY : out[e];
    if (enc_f(mp) == maxp_u[g]) atomicMin(&act_u[g], (unsigned)e);
}

__global__ void k_final(const unsigned* __restrict__ maxp_u, const unsigned* __restrict__ act_u,
                        float* __restrict__ out)
{
    int g = blockIdx.x * 256 + threadIdx.x;
    if (g >= N_GRAPHS) return;
    out[N_EDGES + g] = dec_f(maxp_u[g]);
    out[N_EDGES + N_GRAPHS + g] = (float)act_u[g];
}

// ---------- launch ----------
extern "C" void kernel_launch(void* const* d_in, const int* in_sizes, int n_in,
                              void* d_out, int out_size, void* d_ws, size_t ws_size,
                              hipStream_t stream)
{
    const float* x   = (const float*)d_in[0];
    const int*   ei  = (const int*)d_in[1];
    const int*   src = ei;
    const int*   dst = ei + N_EDGES;
    const unsigned char* state = (const unsigned char*)d_in[2];
    const int*   batch = (const int*)d_in[3];
    const int*   y     = (const int*)d_in[4];
    const float* Wg = (const float*)d_in[5];
    const float* bg = (const float*)d_in[6];
    const float* W1 = (const float*)d_in[7];
    const float* b1 = (const float*)d_in[8];
    const float* W2 = (const float*)d_in[9];
    const float* b2 = (const float*)d_in[10];
    const float* W3 = (const float*)d_in[11];
    const float* b3 = (const float*)d_in[12];
    const float* P1 = (const float*)d_in[13];
    const float* pb1= (const float*)d_in[14];
    const float* P2 = (const float*)d_in[15];
    const float* pb2= (const float*)d_in[16];

    float* ws   = (float*)d_ws;
    float* aggf = ws;                          // 3,200,000 f32
    float* aggo = aggf + 3200000;              // 3,200,000 f32
    float* reps = aggo + 3200000;              // 1,600,000 f32
    float* lg   = reps + 1600000;              //   400,000 f32
    float* ex   = lg   + 400000;               //   400,000 f32
    unsigned* m_u    = (unsigned*)(ex + 400000);   // 500
    float*    denom  = (float*)(m_u + 500);        // 500
    unsigned* maxp_u = (unsigned*)(denom + 500);   // 500
    unsigned* act_u  = maxp_u + 500;               // 500

    hipMemsetAsync(aggf, 0, (size_t)6400000 * 4, stream);          // aggf + aggo
    hipMemsetAsync(m_u, 0, (size_t)1500 * 4, stream);              // m_u, denom, maxp_u
    hipMemsetAsync(act_u, 0xFF, (size_t)500 * 4, stream);          // argmin identity

    k_scatter <<<(N_EDGES * 64) / 256, 256, 0, stream>>>(x, src, dst, state, aggf, aggo);
    k_nodereps<<<N_NODES / 8, 256, 0, stream>>>(x, aggf, aggo, Wg, bg, reps);
    k_mlp     <<<N_EDGES / 32, 256, 0, stream>>>(reps, src, dst, state, batch, y,
                                                 W1, b1, W2, b2, W3, b3, P1, pb1, P2, pb2,
                                                 lg, m_u);
    int gE = (N_EDGES + 255) / 256;
    k_ex     <<<gE, 256, 0, stream>>>(lg, src, state, batch, m_u, ex, denom);
    k_probs  <<<gE, 256, 0, stream>>>(ex, src, state, batch, denom, (float*)d_out, maxp_u);
    k_argmax <<<gE, 256, 0, stream>>>((const float*)d_out, src, state, batch, maxp_u, act_u);
    k_final  <<<(N_GRAPHS + 255) / 256, 256, 0, stream>>>(maxp_u, act_u, (float*)d_out);
}

// Round 2
// 962.174 us; speedup vs baseline: 2.4855x; 2.4855x over previous
//
#include <hip/hip_runtime.h>
#include <math.h>

#define N_NODES  50000
#define N_EDGES  400000
#define N_GRAPHS 500
#define CAND_MAX 262144
#define DELTA    1e-3f

typedef __attribute__((ext_vector_type(8))) short bf16x8;
typedef __attribute__((ext_vector_type(4))) float f32x4;

// ---------- helpers ----------
__device__ __forceinline__ float elu_f(float v) { return v > 0.f ? v : expm1f(v); }

__device__ __forceinline__ unsigned enc_f(float f) {
    unsigned u = __float_as_uint(f);
    return (u & 0x80000000u) ? ~u : (u | 0x80000000u);
}
__device__ __forceinline__ float dec_f(unsigned u) {
    return __uint_as_float((u & 0x80000000u) ? (u & 0x7FFFFFFFu) : ~u);
}
// f32 -> bf16 round-to-nearest-even (bit trick)
__device__ __forceinline__ unsigned short f2bf(float f) {
    unsigned u = __float_as_uint(f);
    return (unsigned short)((u + 0x7FFFu + ((u >> 16) & 1u)) >> 16);
}
__device__ __forceinline__ float bf2f(unsigned short h) {
    return __uint_as_float(((unsigned)h) << 16);
}

// ---------- 1) scatter-add message passing ----------
__global__ void k_scatter(const float* __restrict__ x, const int* __restrict__ src,
                          const int* __restrict__ dst, const unsigned char* __restrict__ state,
                          float* __restrict__ aggf, float* __restrict__ aggo)
{
    unsigned idx = blockIdx.x * 256u + threadIdx.x;
    int e = idx >> 6;
    int j = idx & 63;
    if (e >= N_EDGES) return;
    int s = src[e], d = dst[e];
    float v = x[s * 64 + j];
    atomicAdd(&aggf[d * 64 + j], v);
    if (state[e]) atomicAdd(&aggo[d * 64 + j], v);
}

// ---------- 2) node reps ----------
__global__ void k_nodereps(const float* __restrict__ x, const float* __restrict__ aggf,
                           const float* __restrict__ aggo, const float* __restrict__ Wg,
                           const float* __restrict__ bg, float* __restrict__ reps)
{
    int t = threadIdx.x;
    int n = blockIdx.x * 8 + (t >> 5);
    int o = t & 31;
    if (n >= N_NODES) return;
    const float* xr = x    + n * 64;
    const float* af = aggf + n * 64;
    const float* ao = aggo + n * 64;
    float accf = 0.f, acco = 0.f;
    #pragma unroll 8
    for (int i = 0; i < 64; ++i) {
        float w = Wg[i * 32 + o];
        accf += (xr[i] + af[i]) * w;
        acco += (xr[i] + ao[i]) * w;
    }
    float b = bg[o];
    reps[n * 32 + o] = elu_f(accf + b) - elu_f(acco + b);
}

// ---------- 3) weight prep: split f32 -> (Bh, Bl) bf16, fragment-ordered ----------
// layout per layer: [ps(0:hi,1:lo)][kb][nt][lane][8 bf16] ; frag = 64 lanes * 16B = 1024B
__global__ void k_prep(const float* __restrict__ W1, const float* __restrict__ W2,
                       const float* __restrict__ W3, const float* __restrict__ P1,
                       const float* __restrict__ P2, char* __restrict__ Bpp)
{
    int tid = blockIdx.x * 256 + threadIdx.x;
    if (tid >= 15616) return;
    const float* W; int K, NT, Nreal, base, i;
    if (tid < 4096)       { W = W1; K = 64;  NT = 16; Nreal = 256; base = 0;      i = tid; }
    else if (tid < 12288) { W = W2; K = 256; NT = 8;  Nreal = 128; base = 65536;  i = tid - 4096; }
    else if (tid < 14336) { W = W3; K = 128; NT = 4;  Nreal = 64;  base = 196608; i = tid - 12288; }
    else if (tid < 15360) { W = P1; K = 64;  NT = 4;  Nreal = 64;  base = 229376; i = tid - 14336; }
    else                  { W = P2; K = 64;  NT = 1;  Nreal = 10;  base = 245760; i = tid - 15360; }
    int KB = K / 32;
    int lane = i & 63; int i2 = i >> 6;
    int nt = i2 % NT; int i3 = i2 / NT;
    int kb = i3 % KB; int ps = i3 / KB;
    unsigned short s[8];
    #pragma unroll
    for (int j = 0; j < 8; ++j) {
        int k = kb * 32 + ((lane >> 4) << 3) + j;
        int n = nt * 16 + (lane & 15);
        float wv = (n < Nreal) ? W[k * Nreal + n] : 0.f;
        unsigned short h = f2bf(wv);
        s[j] = ps ? f2bf(wv - bf2f(h)) : h;
    }
    uint4 u;
    u.x = (unsigned)s[0] | ((unsigned)s[1] << 16);
    u.y = (unsigned)s[2] | ((unsigned)s[3] << 16);
    u.z = (unsigned)s[4] | ((unsigned)s[5] << 16);
    u.w = (unsigned)s[6] | ((unsigned)s[7] << 16);
    int frag = (ps * KB + kb) * NT + nt;
    *reinterpret_cast<uint4*>(Bpp + base + frag * 1024 + lane * 16) = u;
}

// ---------- 4) fused MFMA MLP ----------
// 32 edges/block, 4 waves. Activation tiles in LDS as split bf16 (hi tile, lo tile),
// XOR-swizzled: byte ^= (row&7)<<4. 3-term split product: Ah*Bh + Al*Bh + Ah*Bl.
#define OFF_R0 0
#define OFF_R1 8192
#define OFF_R2 40960
#define SM_BYTES 57344

template<int K, int N, int ACT>   // ACT: 0 linear store, 1 elu store, 2 logits f32 store
__device__ __forceinline__ void run_layer(char* sm, const char* gB, int inOff, int outOff,
                                          const float* __restrict__ bias, int w, int lane)
{
    constexpr int KB  = K / 32;
    constexpr int NT  = N / 16;
    constexpr int NTC = (NT < 8) ? NT : 8;
    constexpr int NH  = NT / NTC;
    constexpr int NTW = (NTC >= 4) ? (NTC / 4) : 1;

    __syncthreads();   // previous layer's LDS writes visible

    bf16x8 Ah[2][KB], Al[2][KB];
    {
        const int row0 = (lane & 15);
        const int kb0  = (lane >> 4) * 8;
        #pragma unroll
        for (int mt = 0; mt < 2; ++mt) {
            int row = mt * 16 + row0;
            #pragma unroll
            for (int kb = 0; kb < KB; ++kb) {
                int off = (((row * K + kb * 32 + kb0) * 2) ^ ((row & 7) << 4));
                Ah[mt][kb] = *reinterpret_cast<const bf16x8*>(sm + inOff + off);
                Al[mt][kb] = *reinterpret_cast<const bf16x8*>(sm + inOff + 32 * K * 2 + off);
            }
        }
    }

    #pragma unroll
    for (int nh = 0; nh < NH; ++nh) {
        f32x4 C[2][NTW];
        #pragma unroll
        for (int mt = 0; mt < 2; ++mt)
            #pragma unroll
            for (int q = 0; q < NTW; ++q)
                C[mt][q] = (f32x4){0.f, 0.f, 0.f, 0.f};

        // pass Bh: both Ah and Al
        #pragma unroll
        for (int kb = 0; kb < KB; ++kb) {
            #pragma unroll
            for (int q = 0; q < NTW; ++q) {
                int nt = (w * NTW + q) % NTC;
                bf16x8 Bf = *reinterpret_cast<const bf16x8*>(
                    gB + ((kb * NT + nh * NTC + nt) * 1024) + lane * 16);
                #pragma unroll
                for (int mt = 0; mt < 2; ++mt) {
                    C[mt][q] = __builtin_amdgcn_mfma_f32_16x16x32_bf16(Ah[mt][kb], Bf, C[mt][q], 0, 0, 0);
                    C[mt][q] = __builtin_amdgcn_mfma_f32_16x16x32_bf16(Al[mt][kb], Bf, C[mt][q], 0, 0, 0);
                }
            }
        }
        // pass Bl: Ah only
        #pragma unroll
        for (int kb = 0; kb < KB; ++kb) {
            #pragma unroll
            for (int q = 0; q < NTW; ++q) {
                int nt = (w * NTW + q) % NTC;
                bf16x8 Bf = *reinterpret_cast<const bf16x8*>(
                    gB + (((KB + kb) * NT + nh * NTC + nt) * 1024) + lane * 16);
                #pragma unroll
                for (int mt = 0; mt < 2; ++mt)
                    C[mt][q] = __builtin_amdgcn_mfma_f32_16x16x32_bf16(Ah[mt][kb], Bf, C[mt][q], 0, 0, 0);
            }
        }

        // epilogue
        #pragma unroll
        for (int q = 0; q < NTW; ++q) {
            int nt = (w * NTW + q) % NTC;
            int n  = nh * NTC * 16 + nt * 16 + (lane & 15);
            float b = (ACT == 2) ? (n < 10 ? bias[n] : 0.f) : bias[n];
            #pragma unroll
            for (int mt = 0; mt < 2; ++mt) {
                #pragma unroll
                for (int r = 0; r < 4; ++r) {
                    int row = mt * 16 + (lane >> 4) * 4 + r;
                    float v = C[mt][q][r] + b;
                    if (ACT == 1) v = elu_f(v);
                    if (ACT == 2) {
                        *reinterpret_cast<float*>(sm + outOff + (row * N + n) * 4) = v;
                    } else {
                        unsigned short h = f2bf(v);
                        unsigned short l = f2bf(v - bf2f(h));
                        int off = (((row * N + n) * 2) ^ ((row & 7) << 4));
                        *reinterpret_cast<unsigned short*>(sm + outOff + off) = h;
                        *reinterpret_cast<unsigned short*>(sm + outOff + 32 * N * 2 + off) = l;
                    }
                }
            }
        }
    }
}

__global__ __launch_bounds__(256, 2) void k_mlp(
    const float* __restrict__ reps, const int* __restrict__ src, const int* __restrict__ dst,
    const unsigned char* __restrict__ state, const int* __restrict__ batch, const int* __restrict__ y,
    const float* __restrict__ b1, const float* __restrict__ b2, const float* __restrict__ b3,
    const float* __restrict__ pb1, const float* __restrict__ pb2,
    const char* __restrict__ Bpp, float* __restrict__ lg_out, unsigned* __restrict__ m_u)
{
    __shared__ char sm[SM_BYTES];
    __shared__ int sSrc[32], sDst[32], sG[32], sCol[32], sAvail[32];
    const int t = threadIdx.x, w = t >> 6, lane = t & 63;
    const int ebase = blockIdx.x * 32;

    if (t < 32) {
        int e = ebase + t;
        int s = src[e];
        sSrc[t] = s; sDst[t] = dst[e];
        int g = batch[s]; sG[t] = g; sCol[t] = y[g];
        sAvail[t] = state[e] ? 0 : 1;
    }
    __syncthreads();

    // stage input tile: concat(reps[src], reps[dst]) -> split bf16, swizzled
    {
        int e = t >> 3, f0 = (t & 7) * 8;
        const float* rp = (f0 < 32) ? (reps + sSrc[e] * 32 + f0) : (reps + sDst[e] * 32 + (f0 - 32));
        float4 v0 = *reinterpret_cast<const float4*>(rp);
        float4 v1 = *reinterpret_cast<const float4*>(rp + 4);
        float v[8] = {v0.x, v0.y, v0.z, v0.w, v1.x, v1.y, v1.z, v1.w};
        #pragma unroll
        for (int i = 0; i < 4; ++i) {
            unsigned short h0 = f2bf(v[2*i]),   h1 = f2bf(v[2*i+1]);
            unsigned short l0 = f2bf(v[2*i] - bf2f(h0));
            unsigned short l1 = f2bf(v[2*i+1] - bf2f(h1));
            int off = (((e * 64 + f0 + 2*i) * 2) ^ ((e & 7) << 4));
            *reinterpret_cast<unsigned*>(sm + OFF_R0 + off)        = (unsigned)h0 | ((unsigned)h1 << 16);
            *reinterpret_cast<unsigned*>(sm + OFF_R0 + 4096 + off) = (unsigned)l0 | ((unsigned)l1 << 16);
        }
    }

    run_layer< 64, 256, 1>(sm, Bpp + 0,      OFF_R0, OFF_R1, b1,  w, lane);
    run_layer<256, 128, 1>(sm, Bpp + 65536,  OFF_R1, OFF_R2, b2,  w, lane);
    run_layer<128,  64, 0>(sm, Bpp + 196608, OFF_R2, OFF_R0, b3,  w, lane);
    run_layer< 64,  64, 1>(sm, Bpp + 229376, OFF_R0, OFF_R2, pb1, w, lane);
    run_layer< 64,  16, 2>(sm, Bpp + 245760, OFF_R2, OFF_R1, pb2, w, lane);
    __syncthreads();

    if (t < 32) {
        int col = sCol[t];
        float lg = *reinterpret_cast<const float*>(sm + OFF_R1 + (t * 16 + col) * 4);
        lg_out[ebase + t] = lg;
        float lgm = sAvail[t] ? lg : -INFINITY;
        atomicMax(&m_u[sG[t]], enc_f(lgm));
    }
}

// ---------- 5) softmax pieces + candidate select ----------
__global__ void k_ex(const float* __restrict__ lg, const int* __restrict__ src,
                     const unsigned char* __restrict__ state, const int* __restrict__ batch,
                     const unsigned* __restrict__ m_u, float* __restrict__ ex,
                     float* __restrict__ denom, unsigned* __restrict__ cand,
                     unsigned* __restrict__ ccnt)
{
    int e = blockIdx.x * 256 + threadIdx.x;
    if (e >= N_EDGES) return;
    int g = batch[src[e]];
    float v = 0.f;
    if (!state[e]) {
        float l = lg[e];
        float m = dec_f(m_u[g]);
        v = expf(l - m);
        if (l >= m - DELTA) {
            unsigned i = atomicAdd(ccnt, 1u);
            if (i < CAND_MAX) cand[i] = (unsigned)e;
        }
    }
    ex[e] = v;
    atomicAdd(&denom[g], v);
}

__global__ void k_probs(const float* __restrict__ ex, const int* __restrict__ src,
                        const unsigned char* __restrict__ state, const int* __restrict__ batch,
                        const float* __restrict__ denom, float* __restrict__ out,
                        unsigned* __restrict__ maxp_u)
{
    int e = blockIdx.x * 256 + threadIdx.x;
    if (e >= N_EDGES) return;
    int g = batch[src[e]];
    float p = ex[e] / denom[g];
    out[e] = p;
    float mp = state[e] ? -INFINITY : p;
    atomicMax(&maxp_u[g], enc_f(mp));
}

// ---------- 6) exact f32 recompute for argmax candidates ----------
__global__ __launch_bounds__(256) void k_refine(
    const float* __restrict__ reps, const int* __restrict__ src, const int* __restrict__ dst,
    const int* __restrict__ batch, const int* __restrict__ y,
    const float* __restrict__ W1, const float* __restrict__ b1,
    const float* __restrict__ W2, const float* __restrict__ b2,
    const float* __restrict__ W3, const float* __restrict__ b3,
    const float* __restrict__ P1, const float* __restrict__ pb1,
    const float* __restrict__ P2, const float* __restrict__ pb2,
    const unsigned* __restrict__ cand, const unsigned* __restrict__ ccnt,
    float* __restrict__ candlg, unsigned* __restrict__ refmax_u)
{
    __shared__ float sa[4][256], sb[4][256];
    const int t = threadIdx.x, w = t >> 6, lane = t & 63;
    unsigned cnt = *ccnt; if (cnt > CAND_MAX) cnt = CAND_MAX;
    for (unsigned base = blockIdx.x * 4; base < cnt; base += gridDim.x * 4) {
        unsigned ci = base + w;
        bool act = ci < cnt;
        int e = 0, g = 0, col = 0;
        if (act) {
            e = (int)cand[ci];
            int s_ = src[e], d_ = dst[e];
            g = batch[s_]; col = y[g];
            sa[w][lane] = (lane < 32) ? reps[s_ * 32 + lane] : reps[d_ * 32 + (lane - 32)];
        }
        __syncthreads();
        if (act) {
            float a[4];
            #pragma unroll
            for (int r = 0; r < 4; ++r) {
                int o = lane + 64 * r; float acc = b1[o];
                for (int k = 0; k < 64; ++k) acc += sa[w][k] * W1[k * 256 + o];
                a[r] = elu_f(acc);
            }
            #pragma unroll
            for (int r = 0; r < 4; ++r) sb[w][lane + 64 * r] = a[r];
        }
        __syncthreads();
        if (act) {
            float a0 = b2[lane], a1 = b2[lane + 64];
            for (int k = 0; k < 256; ++k) {
                float s_ = sb[w][k];
                a0 += s_ * W2[k * 128 + lane];
                a1 += s_ * W2[k * 128 + lane + 64];
            }
            sa[w][lane] = elu_f(a0); sa[w][lane + 64] = elu_f(a1);
        }
        __syncthreads();
        if (act) {
            float acc = b3[lane];
            for (int k = 0; k < 128; ++k) acc += sa[w][k] * W3[k * 64 + lane];
            sb[w][lane] = acc;   // no activation
        }
        __syncthreads();
        if (act) {
            float acc = pb1[lane];
            for (int k = 0; k < 64; ++k) acc += sb[w][k] * P1[k * 64 + lane];
            sa[w][lane] = elu_f(acc);
        }
        __syncthreads();
        float part = act ? sa[w][lane] * P2[lane * 10 + col] : 0.f;
        #pragma unroll
        for (int m = 32; m > 0; m >>= 1) part += __shfl_xor(part, m, 64);
        if (act && lane == 0) {
            float lgf = part + pb2[col];
            candlg[ci] = lgf;
            atomicMax(&refmax_u[g], enc_f(lgf));
        }
        __syncthreads();
    }
}

__global__ void k_refine2(const unsigned* __restrict__ cand, const unsigned* __restrict__ ccnt,
                          const float* __restrict__ candlg, const int* __restrict__ src,
                          const int* __restrict__ batch, const unsigned* __restrict__ refmax_u,
                          unsigned* __restrict__ act_u)
{
    unsigned cnt = *ccnt; if (cnt > CAND_MAX) cnt = CAND_MAX;
    for (unsigned ci = blockIdx.x * 256 + threadIdx.x; ci < cnt; ci += gridDim.x * 256) {
        unsigned e = cand[ci];
        int g = batch[src[e]];
        if (enc_f(candlg[ci]) == refmax_u[g]) atomicMin(&act_u[g], e);
    }
}

__global__ void k_final(const unsigned* __restrict__ maxp_u, const unsigned* __restrict__ act_u,
                        float* __restrict__ out)
{
    int g = blockIdx.x * 256 + threadIdx.x;
    if (g >= N_GRAPHS) return;
    out[N_EDGES + g] = dec_f(maxp_u[g]);
    out[N_EDGES + N_GRAPHS + g] = (float)act_u[g];
}

// ---------- launch ----------
extern "C" void kernel_launch(void* const* d_in, const int* in_sizes, int n_in,
                              void* d_out, int out_size, void* d_ws, size_t ws_size,
                              hipStream_t stream)
{
    const float* x   = (const float*)d_in[0];
    const int*   ei  = (const int*)d_in[1];
    const int*   src = ei;
    const int*   dst = ei + N_EDGES;
    const unsigned char* state = (const unsigned char*)d_in[2];
    const int*   batch = (const int*)d_in[3];
    const int*   y     = (const int*)d_in[4];
    const float* Wg = (const float*)d_in[5];
    const float* bg = (const float*)d_in[6];
    const float* W1 = (const float*)d_in[7];
    const float* b1 = (const float*)d_in[8];
    const float* W2 = (const float*)d_in[9];
    const float* b2 = (const float*)d_in[10];
    const float* W3 = (const float*)d_in[11];
    const float* b3 = (const float*)d_in[12];
    const float* P1 = (const float*)d_in[13];
    const float* pb1= (const float*)d_in[14];
    const float* P2 = (const float*)d_in[15];
    const float* pb2= (const float*)d_in[16];

    float* ws   = (float*)d_ws;
    float* aggf = ws;                       // 3,200,000 f32
    float* aggo = ws + 3200000;             // 3,200,000 f32
    float* reps = ws + 6400000;             // 1,600,000 f32
    float* lg   = ws + 8000000;             //   400,000 f32
    float* ex   = ws + 8400000;             //   400,000 f32
    unsigned* S = (unsigned*)(ws + 8800000);
    unsigned* m_u      = S;                 // 500
    float*    denom    = (float*)(S + 500); // 500
    unsigned* maxp_u   = S + 1000;          // 500
    unsigned* refmax_u = S + 1500;          // 500
    unsigned* ccnt     = S + 2000;          // 1
    unsigned* act_u    = S + 2001;          // 500
    char*     Bpp    = (char*)aggo;         // 249,856 B (overlays aggo AFTER k_nodereps)
    unsigned* cand   = (unsigned*)aggf;     // 262,144 u32 (overlays aggf after k_nodereps)
    float*    candlg = (float*)(aggf + 262144);

    hipMemsetAsync(aggf, 0, (size_t)6400000 * 4, stream);   // aggf + aggo
    hipMemsetAsync(S, 0, (size_t)2001 * 4, stream);         // m_u, denom, maxp_u, refmax_u, ccnt
    hipMemsetAsync(act_u, 0xFF, (size_t)500 * 4, stream);   // argmin identity

    k_scatter <<<(N_EDGES * 64) / 256, 256, 0, stream>>>(x, src, dst, state, aggf, aggo);
    k_nodereps<<<N_NODES / 8, 256, 0, stream>>>(x, aggf, aggo, Wg, bg, reps);
    k_prep    <<<61, 256, 0, stream>>>(W1, W2, W3, P1, P2, Bpp);
    k_mlp     <<<N_EDGES / 32, 256, 0, stream>>>(reps, src, dst, state, batch, y,
                                                 b1, b2, b3, pb1, pb2, Bpp, lg, m_u);
    int gE = (N_EDGES + 255) / 256;
    k_ex     <<<gE, 256, 0, stream>>>(lg, src, state, batch, m_u, ex, denom, cand, ccnt);
    k_probs  <<<gE, 256, 0, stream>>>(ex, src, state, batch, denom, (float*)d_out, maxp_u);
    k_refine <<<256, 256, 0, stream>>>(reps, src, dst, batch, y,
                                       W1, b1, W2, b2, W3, b3, P1, pb1, P2, pb2,
                                       cand, ccnt, candlg, refmax_u);
    k_refine2<<<64, 256, 0, stream>>>(cand, ccnt, candlg, src, batch, refmax_u, act_u);
    k_final  <<<2, 256, 0, stream>>>(maxp_u, act_u, (float*)d_out);
}

// Round 3
// 604.695 us; speedup vs baseline: 3.9548x; 1.5912x over previous
//
#include <hip/hip_runtime.h>
#include <math.h>

#define N_NODES  50000
#define N_EDGES  400000
#define N_GRAPHS 500
#define CAND_MAX 262144
#define DELTA    1e-3f
#define CAP      32
#define OVF_MAX  4096

typedef __attribute__((ext_vector_type(8))) short bf16x8;
typedef __attribute__((ext_vector_type(4))) float f32x4;

// ---------- helpers ----------
__device__ __forceinline__ float elu_f(float v) { return v > 0.f ? v : expm1f(v); }   // refine-grade
__device__ __forceinline__ float elu_fast(float v) {
    return fmaxf(v, 0.f) + (__expf(fminf(v, 0.f)) - 1.f);   // branchless, v_exp_f32
}

__device__ __forceinline__ unsigned enc_f(float f) {
    unsigned u = __float_as_uint(f);
    return (u & 0x80000000u) ? ~u : (u | 0x80000000u);
}
__device__ __forceinline__ float dec_f(unsigned u) {
    return __uint_as_float((u & 0x80000000u) ? (u & 0x7FFFFFFFu) : ~u);
}
// f32 -> bf16 RNE
__device__ __forceinline__ unsigned short f2bf(float f) {
    unsigned u = __float_as_uint(f);
    return (unsigned short)((u + 0x7FFFu + ((u >> 16) & 1u)) >> 16);
}
// f32 -> bf16 truncate (cheap; used for lo residual only)
__device__ __forceinline__ unsigned short f2bf_tr(float f) {
    return (unsigned short)(__float_as_uint(f) >> 16);
}
__device__ __forceinline__ float bf2f(unsigned short h) {
    return __uint_as_float(((unsigned)h) << 16);
}

// ---------- 1a) bucket placement: one cheap atomic per edge ----------
__global__ void k_place(const int* __restrict__ dst, unsigned* __restrict__ cnt,
                        unsigned* __restrict__ bucket, unsigned* __restrict__ ovf)
{
    int e = blockIdx.x * 256 + threadIdx.x;
    if (e >= N_EDGES) return;
    int d = dst[e];
    unsigned idx = atomicAdd(&cnt[d], 1u);
    if (idx < CAP) bucket[d * CAP + idx] = (unsigned)e;
    else {
        unsigned oi = atomicAdd(&ovf[0], 1u);
        if (oi < OVF_MAX) { ovf[2 + 2 * oi] = (unsigned)e; ovf[3 + 2 * oi] = (unsigned)d; }
    }
}

// ---------- 1b) gather-aggregate: no atomics, writes aggf/aggo fully ----------
__global__ void k_agg(const float* __restrict__ x, const int* __restrict__ src,
                      const unsigned char* __restrict__ state, const unsigned* __restrict__ cnt,
                      const unsigned* __restrict__ bucket,
                      float* __restrict__ aggf, float* __restrict__ aggo)
{
    int n = blockIdx.x * 4 + (threadIdx.x >> 6);
    int j = threadIdx.x & 63;
    unsigned c = cnt[n]; if (c > CAP) c = CAP;
    float sf = 0.f, so = 0.f;
    for (unsigned i = 0; i < c; ++i) {
        unsigned e = bucket[n * CAP + i];
        float v = x[src[e] * 64 + j];
        sf += v;
        if (state[e]) so += v;
    }
    aggf[n * 64 + j] = sf;
    aggo[n * 64 + j] = so;
}

// ---------- 1c) overflow edges (deg > CAP): rare/none, exactness fallback ----------
__global__ void k_ovf(const float* __restrict__ x, const int* __restrict__ src,
                      const unsigned char* __restrict__ state, const unsigned* __restrict__ ovf,
                      float* __restrict__ aggf, float* __restrict__ aggo)
{
    unsigned c = ovf[0]; if (c > OVF_MAX) c = OVF_MAX;
    for (unsigned i = blockIdx.x * 256 + threadIdx.x; i < c * 64; i += gridDim.x * 256) {
        unsigned oi = i >> 6; int j = i & 63;
        unsigned e = ovf[2 + 2 * oi];
        int d = (int)ovf[3 + 2 * oi];
        float v = x[src[e] * 64 + j];
        atomicAdd(&aggf[d * 64 + j], v);
        if (state[e]) atomicAdd(&aggo[d * 64 + j], v);
    }
}

// ---------- 2) node reps ----------
__global__ void k_nodereps(const float* __restrict__ x, const float* __restrict__ aggf,
                           const float* __restrict__ aggo, const float* __restrict__ Wg,
                           const float* __restrict__ bg, float* __restrict__ reps)
{
    int t = threadIdx.x;
    int n = blockIdx.x * 8 + (t >> 5);
    int o = t & 31;
    if (n >= N_NODES) return;
    const float* xr = x    + n * 64;
    const float* af = aggf + n * 64;
    const float* ao = aggo + n * 64;
    float accf = 0.f, acco = 0.f;
    #pragma unroll 8
    for (int i = 0; i < 64; ++i) {
        float w = Wg[i * 32 + o];
        accf += (xr[i] + af[i]) * w;
        acco += (xr[i] + ao[i]) * w;
    }
    float b = bg[o];
    reps[n * 32 + o] = elu_fast(accf + b) - elu_fast(acco + b);
}

// ---------- 3) weight prep: split f32 -> (Bh, Bl) bf16, fragment-ordered ----------
__global__ void k_prep(const float* __restrict__ W1, const float* __restrict__ W2,
                       const float* __restrict__ W3, const float* __restrict__ P1,
                       const float* __restrict__ P2, char* __restrict__ Bpp)
{
    int tid = blockIdx.x * 256 + threadIdx.x;
    if (tid >= 15616) return;
    const float* W; int K, NT, Nreal, base, i;
    if (tid < 4096)       { W = W1; K = 64;  NT = 16; Nreal = 256; base = 0;      i = tid; }
    else if (tid < 12288) { W = W2; K = 256; NT = 8;  Nreal = 128; base = 65536;  i = tid - 4096; }
    else if (tid < 14336) { W = W3; K = 128; NT = 4;  Nreal = 64;  base = 196608; i = tid - 12288; }
    else if (tid < 15360) { W = P1; K = 64;  NT = 4;  Nreal = 64;  base = 229376; i = tid - 14336; }
    else                  { W = P2; K = 64;  NT = 1;  Nreal = 10;  base = 245760; i = tid - 15360; }
    int KB = K / 32;
    int lane = i & 63; int i2 = i >> 6;
    int nt = i2 % NT; int i3 = i2 / NT;
    int kb = i3 % KB; int ps = i3 / KB;
    unsigned short s[8];
    #pragma unroll
    for (int j = 0; j < 8; ++j) {
        int k = kb * 32 + ((lane >> 4) << 3) + j;
        int n = nt * 16 + (lane & 15);
        float wv = (n < Nreal) ? W[k * Nreal + n] : 0.f;
        unsigned short h = f2bf(wv);
        s[j] = ps ? f2bf(wv - bf2f(h)) : h;
    }
    uint4 u;
    u.x = (unsigned)s[0] | ((unsigned)s[1] << 16);
    u.y = (unsigned)s[2] | ((unsigned)s[3] << 16);
    u.z = (unsigned)s[4] | ((unsigned)s[5] << 16);
    u.w = (unsigned)s[6] | ((unsigned)s[7] << 16);
    int frag = (ps * KB + kb) * NT + nt;
    *reinterpret_cast<uint4*>(Bpp + base + frag * 1024 + lane * 16) = u;
}

// ---------- 4) fused MFMA MLP ----------
#define OFF_R0 0
#define OFF_R1 8192
#define OFF_R2 40960
#define SM_BYTES 57344

template<int K, int N, int ACT>   // ACT: 0 linear, 1 elu, 2 logits f32 store
__device__ __forceinline__ void run_layer(char* sm, const char* gB, int inOff, int outOff,
                                          const float* __restrict__ bias, int w, int lane)
{
    constexpr int KB  = K / 32;
    constexpr int NT  = N / 16;
    constexpr int NTC = (NT < 8) ? NT : 8;
    constexpr int NH  = NT / NTC;
    constexpr int NTW = (NTC >= 4) ? (NTC / 4) : 1;

    __syncthreads();

    bf16x8 Ah[2][KB], Al[2][KB];
    {
        const int row0 = (lane & 15);
        const int kb0  = (lane >> 4) * 8;
        #pragma unroll
        for (int mt = 0; mt < 2; ++mt) {
            int row = mt * 16 + row0;
            #pragma unroll
            for (int kb = 0; kb < KB; ++kb) {
                int off = (((row * K + kb * 32 + kb0) * 2) ^ ((row & 7) << 4));
                Ah[mt][kb] = *reinterpret_cast<const bf16x8*>(sm + inOff + off);
                Al[mt][kb] = *reinterpret_cast<const bf16x8*>(sm + inOff + 32 * K * 2 + off);
            }
        }
    }

    #pragma unroll
    for (int nh = 0; nh < NH; ++nh) {
        f32x4 C[2][NTW];
        #pragma unroll
        for (int q = 0; q < NTW; ++q) {
            int nt = (w * NTW + q) % NTC;
            int n  = nh * NTC * 16 + nt * 16 + (lane & 15);
            float b = (ACT == 2) ? (n < 10 ? bias[n] : 0.f) : bias[n];
            #pragma unroll
            for (int mt = 0; mt < 2; ++mt)
                C[mt][q] = (f32x4){b, b, b, b};
        }

        // pass Bh: both Ah and Al
        #pragma unroll
        for (int kb = 0; kb < KB; ++kb) {
            #pragma unroll
            for (int q = 0; q < NTW; ++q) {
                int nt = (w * NTW + q) % NTC;
                bf16x8 Bf = *reinterpret_cast<const bf16x8*>(
                    gB + ((kb * NT + nh * NTC + nt) * 1024) + lane * 16);
                #pragma unroll
                for (int mt = 0; mt < 2; ++mt) {
                    C[mt][q] = __builtin_amdgcn_mfma_f32_16x16x32_bf16(Ah[mt][kb], Bf, C[mt][q], 0, 0, 0);
                    C[mt][q] = __builtin_amdgcn_mfma_f32_16x16x32_bf16(Al[mt][kb], Bf, C[mt][q], 0, 0, 0);
                }
            }
        }
        // pass Bl: Ah only
        #pragma unroll
        for (int kb = 0; kb < KB; ++kb) {
            #pragma unroll
            for (int q = 0; q < NTW; ++q) {
                int nt = (w * NTW + q) % NTC;
                bf16x8 Bf = *reinterpret_cast<const bf16x8*>(
                    gB + (((KB + kb) * NT + nh * NTC + nt) * 1024) + lane * 16);
                #pragma unroll
                for (int mt = 0; mt < 2; ++mt)
                    C[mt][q] = __builtin_amdgcn_mfma_f32_16x16x32_bf16(Ah[mt][kb], Bf, C[mt][q], 0, 0, 0);
            }
        }

        // epilogue
        #pragma unroll
        for (int q = 0; q < NTW; ++q) {
            int nt = (w * NTW + q) % NTC;
            int n  = nh * NTC * 16 + nt * 16 + (lane & 15);
            #pragma unroll
            for (int mt = 0; mt < 2; ++mt) {
                #pragma unroll
                for (int r = 0; r < 4; ++r) {
                    int row = mt * 16 + (lane >> 4) * 4 + r;
                    float v = C[mt][q][r];
                    if (ACT == 1) v = elu_fast(v);
                    if (ACT == 2) {
                        *reinterpret_cast<float*>(sm + outOff + (row * N + n) * 4) = v;
                    } else {
                        unsigned short h = f2bf(v);
                        unsigned short l = f2bf_tr(v - bf2f(h));
                        int off = (((row * N + n) * 2) ^ ((row & 7) << 4));
                        *reinterpret_cast<unsigned short*>(sm + outOff + off) = h;
                        *reinterpret_cast<unsigned short*>(sm + outOff + 32 * N * 2 + off) = l;
                    }
                }
            }
        }
    }
}

__global__ __launch_bounds__(256, 2) void k_mlp(
    const float* __restrict__ reps, const int* __restrict__ src, const int* __restrict__ dst,
    const unsigned char* __restrict__ state, const int* __restrict__ batch, const int* __restrict__ y,
    const float* __restrict__ b1, const float* __restrict__ b2, const float* __restrict__ b3,
    const float* __restrict__ pb1, const float* __restrict__ pb2,
    const char* __restrict__ Bpp, float* __restrict__ lg_out, unsigned* __restrict__ m_u)
{
    __shared__ char sm[SM_BYTES];
    __shared__ int sSrc[32], sDst[32], sG[32], sCol[32], sAvail[32];
    const int t = threadIdx.x, w = t >> 6, lane = t & 63;
    const int ebase = blockIdx.x * 32;

    if (t < 32) {
        int e = ebase + t;
        int s = src[e];
        sSrc[t] = s; sDst[t] = dst[e];
        int g = batch[s]; sG[t] = g; sCol[t] = y[g];
        sAvail[t] = state[e] ? 0 : 1;
    }
    __syncthreads();

    {
        int e = t >> 3, f0 = (t & 7) * 8;
        const float* rp = (f0 < 32) ? (reps + sSrc[e] * 32 + f0) : (reps + sDst[e] * 32 + (f0 - 32));
        float4 v0 = *reinterpret_cast<const float4*>(rp);
        float4 v1 = *reinterpret_cast<const float4*>(rp + 4);
        float v[8] = {v0.x, v0.y, v0.z, v0.w, v1.x, v1.y, v1.z, v1.w};
        #pragma unroll
        for (int i = 0; i < 4; ++i) {
            unsigned short h0 = f2bf(v[2*i]),   h1 = f2bf(v[2*i+1]);
            unsigned short l0 = f2bf_tr(v[2*i] - bf2f(h0));
            unsigned short l1 = f2bf_tr(v[2*i+1] - bf2f(h1));
            int off = (((e * 64 + f0 + 2*i) * 2) ^ ((e & 7) << 4));
            *reinterpret_cast<unsigned*>(sm + OFF_R0 + off)        = (unsigned)h0 | ((unsigned)h1 << 16);
            *reinterpret_cast<unsigned*>(sm + OFF_R0 + 4096 + off) = (unsigned)l0 | ((unsigned)l1 << 16);
        }
    }

    run_layer< 64, 256, 1>(sm, Bpp + 0,      OFF_R0, OFF_R1, b1,  w, lane);
    run_layer<256, 128, 1>(sm, Bpp + 65536,  OFF_R1, OFF_R2, b2,  w, lane);
    run_layer<128,  64, 0>(sm, Bpp + 196608, OFF_R2, OFF_R0, b3,  w, lane);
    run_layer< 64,  64, 1>(sm, Bpp + 229376, OFF_R0, OFF_R2, pb1, w, lane);
    run_layer< 64,  16, 2>(sm, Bpp + 245760, OFF_R2, OFF_R1, pb2, w, lane);
    __syncthreads();

    if (t < 32) {
        int col = sCol[t];
        float lg = *reinterpret_cast<const float*>(sm + OFF_R1 + (t * 16 + col) * 4);
        lg_out[ebase + t] = lg;
        float lgm = sAvail[t] ? lg : -INFINITY;
        atomicMax(&m_u[sG[t]], enc_f(lgm));
    }
}

// ---------- 5) exp + LDS-bucketed denom + candidate select ----------
__global__ void k_ex(const float* __restrict__ lg, const int* __restrict__ src,
                     const unsigned char* __restrict__ state, const int* __restrict__ batch,
                     const unsigned* __restrict__ m_u, float* __restrict__ ex,
                     float* __restrict__ denom, unsigned* __restrict__ cand,
                     unsigned* __restrict__ ccnt)
{
    __shared__ float sden[N_GRAPHS];
    for (int i = threadIdx.x; i < N_GRAPHS; i += 256) sden[i] = 0.f;
    __syncthreads();
    for (int e = blockIdx.x * 256 + threadIdx.x; e < N_EDGES; e += gridDim.x * 256) {
        int g = batch[src[e]];
        float v = 0.f;
        if (!state[e]) {
            float l = lg[e];
            float m = dec_f(m_u[g]);
            v = __expf(l - m);
            if (l >= m - DELTA) {
                unsigned i = atomicAdd(ccnt, 1u);
                if (i < CAND_MAX) cand[i] = (unsigned)e;
            }
        }
        ex[e] = v;
        atomicAdd(&sden[g], v);
    }
    __syncthreads();
    for (int i = threadIdx.x; i < N_GRAPHS; i += 256)
        if (sden[i] != 0.f) atomicAdd(&denom[i], sden[i]);
}

// ---------- 6) probs (pure elementwise; max prob is 1/denom closed-form) ----------
__global__ void k_probs(const float* __restrict__ ex, const int* __restrict__ src,
                        const int* __restrict__ batch, const float* __restrict__ denom,
                        float* __restrict__ out)
{
    int e = blockIdx.x * 256 + threadIdx.x;
    if (e >= N_EDGES) return;
    int g = batch[src[e]];
    out[e] = ex[e] / denom[g];
}

// ---------- 7) exact f32 recompute for argmax candidates ----------
__global__ __launch_bounds__(256) void k_refine(
    const float* __restrict__ reps, const int* __restrict__ src, const int* __restrict__ dst,
    const int* __restrict__ batch, const int* __restrict__ y,
    const float* __restrict__ W1, const float* __restrict__ b1,
    const float* __restrict__ W2, const float* __restrict__ b2,
    const float* __restrict__ W3, const float* __restrict__ b3,
    const float* __restrict__ P1, const float* __restrict__ pb1,
    const float* __restrict__ P2, const float* __restrict__ pb2,
    const unsigned* __restrict__ cand, const unsigned* __restrict__ ccnt,
    float* __restrict__ candlg, unsigned* __restrict__ refmax_u)
{
    __shared__ float sa[4][256], sb[4][256];
    const int t = threadIdx.x, w = t >> 6, lane = t & 63;
    unsigned cnt = *ccnt; if (cnt > CAND_MAX) cnt = CAND_MAX;
    for (unsigned base = blockIdx.x * 4; base < cnt; base += gridDim.x * 4) {
        unsigned ci = base + w;
        bool act = ci < cnt;
        int e = 0, g = 0, col = 0;
        if (act) {
            e = (int)cand[ci];
            int s_ = src[e], d_ = dst[e];
            g = batch[s_]; col = y[g];
            sa[w][lane] = (lane < 32) ? reps[s_ * 32 + lane] : reps[d_ * 32 + (lane - 32)];
        }
        __syncthreads();
        if (act) {
            float a[4];
            #pragma unroll
            for (int r = 0; r < 4; ++r) {
                int o = lane + 64 * r; float acc = b1[o];
                for (int k = 0; k < 64; ++k) acc += sa[w][k] * W1[k * 256 + o];
                a[r] = elu_f(acc);
            }
            #pragma unroll
            for (int r = 0; r < 4; ++r) sb[w][lane + 64 * r] = a[r];
        }
        __syncthreads();
        if (act) {
            float a0 = b2[lane], a1 = b2[lane + 64];
            for (int k = 0; k < 256; ++k) {
                float s_ = sb[w][k];
                a0 += s_ * W2[k * 128 + lane];
                a1 += s_ * W2[k * 128 + lane + 64];
            }
            sa[w][lane] = elu_f(a0); sa[w][lane + 64] = elu_f(a1);
        }
        __syncthreads();
        if (act) {
            float acc = b3[lane];
            for (int k = 0; k < 128; ++k) acc += sa[w][k] * W3[k * 64 + lane];
            sb[w][lane] = acc;
        }
        __syncthreads();
        if (act) {
            float acc = pb1[lane];
            for (int k = 0; k < 64; ++k) acc += sb[w][k] * P1[k * 64 + lane];
            sa[w][lane] = elu_f(acc);
        }
        __syncthreads();
        float part = act ? sa[w][lane] * P2[lane * 10 + col] : 0.f;
        #pragma unroll
        for (int m = 32; m > 0; m >>= 1) part += __shfl_xor(part, m, 64);
        if (act && lane == 0) {
            float lgf = part + pb2[col];
            candlg[ci] = lgf;
            atomicMax(&refmax_u[g], enc_f(lgf));
        }
        __syncthreads();
    }
}

__global__ void k_refine2(const unsigned* __restrict__ cand, const unsigned* __restrict__ ccnt,
                          const float* __restrict__ candlg, const int* __restrict__ src,
                          const int* __restrict__ batch, const unsigned* __restrict__ refmax_u,
                          unsigned* __restrict__ act_u)
{
    unsigned cnt = *ccnt; if (cnt > CAND_MAX) cnt = CAND_MAX;
    for (unsigned ci = blockIdx.x * 256 + threadIdx.x; ci < cnt; ci += gridDim.x * 256) {
        unsigned e = cand[ci];
        int g = batch[src[e]];
        if (enc_f(candlg[ci]) == refmax_u[g]) atomicMin(&act_u[g], e);
    }
}

__global__ void k_final(const float* __restrict__ denom, const unsigned* __restrict__ act_u,
                        float* __restrict__ out)
{
    int g = blockIdx.x * 256 + threadIdx.x;
    if (g >= N_GRAPHS) return;
    out[N_EDGES + g] = 1.0f / denom[g];
    out[N_EDGES + N_GRAPHS + g] = (float)act_u[g];
}

// ---------- launch ----------
extern "C" void kernel_launch(void* const* d_in, const int* in_sizes, int n_in,
                              void* d_out, int out_size, void* d_ws, size_t ws_size,
                              hipStream_t stream)
{
    const float* x   = (const float*)d_in[0];
    const int*   ei  = (const int*)d_in[1];
    const int*   src = ei;
    const int*   dst = ei + N_EDGES;
    const unsigned char* state = (const unsigned char*)d_in[2];
    const int*   batch = (const int*)d_in[3];
    const int*   y     = (const int*)d_in[4];
    const float* Wg = (const float*)d_in[5];
    const float* bg = (const float*)d_in[6];
    const float* W1 = (const float*)d_in[7];
    const float* b1 = (const float*)d_in[8];
    const float* W2 = (const float*)d_in[9];
    const float* b2 = (const float*)d_in[10];
    const float* W3 = (const float*)d_in[11];
    const float* b3 = (const float*)d_in[12];
    const float* P1 = (const float*)d_in[13];
    const float* pb1= (const float*)d_in[14];
    const float* P2 = (const float*)d_in[15];
    const float* pb2= (const float*)d_in[16];

    float* ws = (float*)d_ws;
    float*    aggf   = ws;                              // 3,200,000 f32
    float*    aggo   = ws + 3200000;                    // 3,200,000 f32
    unsigned* bucket = (unsigned*)(ws + 6400000);       // 1,600,000 u32 (dead after k_agg)
    float*    reps   = ws + 6400000;                    // 1,600,000 f32 (overlays bucket)
    float*    lg     = ws + 8000000;                    //   400,000 f32
    float*    ex     = ws + 8400000;                    //   400,000 f32
    unsigned* cnt    = (unsigned*)(ws + 8800000);       //    50,000 u32
    unsigned* ovf    = (unsigned*)(ws + 8850000);       // 2 + 2*4096
    unsigned* m_u      = (unsigned*)(ws + 8858200);     // 500
    float*    denom    = (float*)(ws + 8858700);        // 500
    unsigned* refmax_u = (unsigned*)(ws + 8859200);     // 500
    unsigned* ccnt     = (unsigned*)(ws + 8859700);     // 1
    unsigned* act_u    = (unsigned*)(ws + 8859701);     // 500
    char*     Bpp      = (char*)(ws + 8860208);         // 249,856 B (16B-aligned)
    unsigned* cand   = (unsigned*)aggf;                 // 262,144 u32 (aggf dead after k_nodereps)
    float*    candlg = aggf + 262144;

    // zero: cnt, ovf, m_u, denom, refmax_u, ccnt (contiguous)
    hipMemsetAsync(cnt, 0, (size_t)(8859701 - 8800000) * 4, stream);
    hipMemsetAsync(act_u, 0xFF, (size_t)500 * 4, stream);

    k_place   <<<(N_EDGES + 255) / 256, 256, 0, stream>>>(dst, cnt, bucket, ovf);
    k_agg     <<<N_NODES / 4, 256, 0, stream>>>(x, src, state, cnt, bucket, aggf, aggo);
    k_ovf     <<<8, 256, 0, stream>>>(x, src, state, ovf, aggf, aggo);
    k_nodereps<<<N_NODES / 8, 256, 0, stream>>>(x, aggf, aggo, Wg, bg, reps);
    k_prep    <<<61, 256, 0, stream>>>(W1, W2, W3, P1, P2, Bpp);
    k_mlp     <<<N_EDGES / 32, 256, 0, stream>>>(reps, src, dst, state, batch, y,
                                                 b1, b2, b3, pb1, pb2, Bpp, lg, m_u);
    k_ex     <<<128, 256, 0, stream>>>(lg, src, state, batch, m_u, ex, denom, cand, ccnt);
    k_probs  <<<(N_EDGES + 255) / 256, 256, 0, stream>>>(ex, src, batch, denom, (float*)d_out);
    k_refine <<<256, 256, 0, stream>>>(reps, src, dst, batch, y,
                                       W1, b1, W2, b2, W3, b3, P1, pb1, P2, pb2,
                                       cand, ccnt, candlg, refmax_u);
    k_refine2<<<64, 256, 0, stream>>>(cand, ccnt, candlg, src, batch, refmax_u, act_u);
    k_final  <<<2, 256, 0, stream>>>(denom, act_u, (float*)d_out);
}